// Round 9
// baseline (126.547 us; speedup 1.0000x reference)
//
#include <hip/hip_runtime.h>

// LocalConnectivity: out[i][j] = sum_{1<=|dx|+|dy|<=5} w_{|dx|+|dy|} * s[(i+dx)&4095][(j+dy)&4095]
// Separable: out[i][j] = sum_{dx=-5..5} r^|dx| * H_{5-|dx|}[i+dx][j] - s[i][j],
//   H_k[t][j] = sum_{|dy|<=k} r^|dy| s[t][j+dy]
//
// Trajectory: R12 (register streaming, VGPR 80, occ 25%) = 57us: 14 SERIAL
// load->wait->compute round trips/wave; lifetime = 14 x ~500cy L3 latency.
// R13/R14 (LDS staging) = 43-55us: chain collapsed to 1 batch but LDS capped
// residency at 8 waves/CU; drain idles half. Nothing saturated anywhere.
// R15: keep R12's high-residency register structure, kill the chain with a
// DEPTH-4 rotating row-buffer pipeline: issue row r+4's 5 loads after
// computing row r -> load-to-use distance ~3 compute iters (~540cy) covers L3
// latency; compiler emits partial vmcnt waits; ~12KB/wave in flight (vs 1KB).
// All buffer indices static after full unroll (r&3). VGPR target < 128.
// R16: R15 bench was an infra failure (container), not a kernel fault
// (audited: coverage exact, no OOB, no sync, all indices static). Resubmit.

#define GMASK  4095
#define RCHUNK 4            // output rows per thread
#define COLS   4            // output cols per thread
#define NR     (RCHUNK + 10)   // 14 input rows streamed
#define DEPTH  4            // pipeline depth (rows in flight)

typedef float f4 __attribute__((ext_vector_type(4), aligned(16)));

__device__ __forceinline__ float uniform_f(float x) {
    union { float f; int i; } u;
    u.f = x;
    u.i = __builtin_amdgcn_readfirstlane(u.i);   // pin in SGPR (wave-uniform)
    return u.f;
}

__global__ __launch_bounds__(256)
void diamond_stencil(const float* __restrict__ s, const float* __restrict__ w,
                     float* __restrict__ out)
{
    const int tid = threadIdx.x;

    // XCD band swizzle (proven in R8/R12): XCD k owns y-chunks [k*128,(k+1)*128),
    // strips fastest -> halo-sharing neighbors co-resident in one 4MiB L2.
    const int bid = blockIdx.x;              // 0..4095
    const int xcd = bid & 7;
    const int idx = bid >> 3;                // 0..511 within this XCD
    const int bx  = idx & 3;                 // column strip (1024 cols each)
    const int by  = xcd * 128 + (idx >> 2);  // y-chunk, contiguous band per XCD

    const int j0  = bx * 1024 + tid * COLS;  // 4 cols per thread, 16B-aligned
    const int t0  = by * RCHUNK;             // 4 output rows per thread

    // wrapped column bases (vec4 bases stay 16B-aligned; wrap only at grid edge)
    const int cL  = (j0 - 5) & GMASK;        // scalar left halo
    const int cm4 = (j0 - 4) & GMASK;
    const int cp4 = (j0 + 4) & GMASK;
    const int cR  = (j0 + 8) & GMASK;        // scalar right halo

    float wgt[6];
    wgt[0] = 1.0f;
#pragma unroll
    for (int d = 1; d <= 5; ++d) wgt[d] = uniform_f(w[d - 1]);   // exp(-d/2)

    float acc[RCHUNK][COLS];
#pragma unroll
    for (int a = 0; a < RCHUNK; ++a)
#pragma unroll
        for (int c = 0; c < COLS; ++c) acc[a][c] = 0.0f;

    // rotating row buffers: 14 floats each (L | A.xyzw | B.xyzw | C.xyzw | R)
    f4    bA[DEPTH], bB[DEPTH], bC[DEPTH];
    float bL[DEPTH], bR[DEPTH];

    // ---- prologue: issue loads for rows 0..DEPTH-1 (all independent) ----
#pragma unroll
    for (int r = 0; r < DEPTH; ++r) {
        const float* row = s + ((size_t)((t0 - 5 + r) & GMASK) << 12);
        bL[r] = row[cL];
        bA[r] = *(const f4*)(row + cm4);
        bB[r] = *(const f4*)(row + j0);
        bC[r] = *(const f4*)(row + cp4);
        bR[r] = row[cR];
    }

    // ---- steady state: compute row r from buf[r&3], refill with row r+4 ----
#pragma unroll
    for (int r = 0; r < NR; ++r) {
        const int b = r & (DEPTH - 1);       // compile-time after unroll

        float f[14];
        f[0]  = bL[b];
        f[1]  = bA[b].x; f[2]  = bA[b].y; f[3]  = bA[b].z; f[4]  = bA[b].w;
        f[5]  = bB[b].x; f[6]  = bB[b].y; f[7]  = bB[b].z; f[8]  = bB[b].w;
        f[9]  = bC[b].x; f[10] = bC[b].y; f[11] = bC[b].z; f[12] = bC[b].w;
        f[13] = bR[b];

        // refill this slot with row r+DEPTH (issued before the heavy ALU block
        // so the loads overlap the compute of rows r..r+3)
        if (r + DEPTH < NR) {
            const float* row = s + ((size_t)((t0 - 5 + r + DEPTH) & GMASK) << 12);
            bL[b] = row[cL];
            bA[b] = *(const f4*)(row + cm4);
            bB[b] = *(const f4*)(row + j0);
            bC[b] = *(const f4*)(row + cp4);
            bR[b] = row[cR];
        }

#pragma unroll
        for (int c = 0; c < COLS; ++c) {
            const float ctr = f[5 + c];
            float Hs[6];
            Hs[0] = ctr;
#pragma unroll
            for (int k = 1; k <= 5; ++k)
                Hs[k] = Hs[k - 1] + wgt[k] * (f[5 + c - k] + f[5 + c + k]);

            // input row t = t0-5+r feeds output row o = t0+a iff |r-5-a| <= 5
#pragma unroll
            for (int a = 0; a < RCHUNK; ++a) {
                const int d = r - 5 - a;     // compile-time
                if (d < -5 || d > 5) continue;
                if (d == 0)
                    acc[a][c] += Hs[5] - ctr;          // center excluded
                else {
                    const int ad = d < 0 ? -d : d;
                    acc[a][c] += wgt[ad] * Hs[5 - ad];
                }
            }
        }
    }

    // store 4 rows x 4 cols, nontemporal (don't thrash L2/L3 read set)
#pragma unroll
    for (int a = 0; a < RCHUNK; ++a) {
        float* op = out + ((size_t)(t0 + a) << 12) + j0;
        f4 r0;
        r0.x = acc[a][0]; r0.y = acc[a][1]; r0.z = acc[a][2]; r0.w = acc[a][3];
        __builtin_nontemporal_store(r0, (f4*)op);
    }
}

extern "C" void kernel_launch(void* const* d_in, const int* in_sizes, int n_in,
                              void* d_out, int out_size, void* d_ws, size_t ws_size,
                              hipStream_t stream)
{
    const float* s = (const float*)d_in[0];   // grid_spikes [4096*4096] f32
    const float* w = (const float*)d_in[1];   // distance_weights [5] f32
    float* out = (float*)d_out;               // [4096*4096] f32

    // 4096 blocks = 4 col strips x 1024 row-chunks, XCD-band swizzled in-kernel
    dim3 grid(4096);
    dim3 block(256);
    diamond_stencil<<<grid, block, 0, stream>>>(s, w, out);
}